// Round 6
// baseline (404.604 us; speedup 1.0000x reference)
//
#include <hip/hip_runtime.h>

typedef unsigned short u16;
typedef __attribute__((ext_vector_type(8))) __bf16 bf16x8;
typedef __attribute__((ext_vector_type(4))) float f32x4;
typedef __attribute__((ext_vector_type(8))) u16 u16x8;
typedef __attribute__((ext_vector_type(4))) u16 u16x4;

#define DIMSZ 1024
#define HEADS 16
#define BLKSZ 129
#define NBLK 32
#define NTOK (BLKSZ * NBLK)      // 4128
#define BATCH 4
#define MROWS (BATCH * NTOK)     // 16512

#define MFMA __builtin_amdgcn_mfma_f32_16x16x32_bf16

#define SSTR 152   // S/P LDS row stride (bf16): 2-way bank alias only (free)
#define KSTR 72    // K tile LDS row stride

#define NKT 32     // K tiles of 32: 1024/32
#define NPH 32     // qkv256 phases: 1024 / 32-k per phase

__device__ __forceinline__ float bf2f(u16 u) {
  return __uint_as_float(((unsigned)u) << 16);
}
__device__ __forceinline__ u16 f2bf(float f) {
  unsigned u = __float_as_uint(f);
  u += 0x7FFFu + ((u >> 16) & 1u);   // round-to-nearest-even
  return (u16)(u >> 16);
}

// async global->LDS, 16B/lane; LDS dest = wave-uniform base + lane*16 (m97)
#define GLD16(ldsp, gp) __builtin_amdgcn_global_load_lds( \
    (const __attribute__((address_space(1))) void*)(gp),   \
    (__attribute__((address_space(3))) void*)(ldsp), 16, 0, 0)

// ---------------------------------------------------------------------------
// f32 -> bf16 cast, 4 elems/thread. n multiple of 1024.
// ---------------------------------------------------------------------------
__global__ __launch_bounds__(256) void cast_f32_bf16(
    const float* __restrict__ in, u16* __restrict__ out, int n)
{
  int i = (blockIdx.x * 256 + threadIdx.x) * 4;
  if (i < n) {
    float4 f = *(const float4*)(in + i);
    u16x4 o = { f2bf(f.x), f2bf(f.y), f2bf(f.z), f2bf(f.w) };
    *(u16x4*)(out + i) = o;
  }
}

// Fused Wq/Wk/Wv cast: out is the contiguous Wqkv16 [3][1024][1024].
__global__ __launch_bounds__(256) void cast_w3(
    const float* __restrict__ a, const float* __restrict__ b,
    const float* __restrict__ c, u16* __restrict__ out)
{
  const int nw = DIMSZ * DIMSZ;
  int i = (blockIdx.x * 256 + threadIdx.x) * 4;
  const float* src = (i < nw) ? a : (i < 2 * nw ? b : c);
  int j = (i < nw) ? i : (i < 2 * nw ? i - nw : i - 2 * nw);
  float4 f = *(const float4*)(src + j);
  u16x4 o = { f2bf(f.x), f2bf(f.y), f2bf(f.z), f2bf(f.w) };
  *(u16x4*)(out + i) = o;
}

// ---------------------------------------------------------------------------
// Bijective XCD-aware block swizzle (m204): contiguous logical chunk per XCD.
// ---------------------------------------------------------------------------
__device__ __forceinline__ int xcd_swz(int bid, int nwg) {
  const int xcd = bid & 7, l = bid >> 3;
  const int q = nwg >> 3, r = nwg & 7;
  return (xcd < r ? xcd * (q + 1) : r * (q + 1) + (xcd - r) * q) + l;
}

// ===========================================================================
// QKV: 256x256 tile, BK(phase)=32, 512 threads = 8 waves (2M x 4N), wave
// tile 128x64 (acc[8][4]).  K-HALF-SPLIT phase schedule (m201-derived):
//   pair(g) = { A[256 rows][32 k] , B[256 rows][32 k] } = 32 KB slot,
//   4-slot ring (128 KB, 1 WG/CU).  Phase g: { ds_read 12 frags from
//   slot g&3 | stage pair g+2 | barrier | 32 MFMA | vmcnt(4) | barrier }.
// Why this works where r3's quadrant split failed: each wave (wm,wn) reads
// ONLY its A-half and B-half, and a K-half pair is a self-contained phase
// unit -> vmcnt(4) at phase end retires exactly pair g+1 (counted, never 0
// mid-loop, T4).  Pre-MFMA barrier creates the wave role-split T5 needs.
// Ring hazard: stage at g overwrites slot of phase g-2, whose reads all
// completed before g-2's end barrier (2 barriers earlier) -> race-free.
// Accumulation K-order identical to prior rounds -> bitwise-same output.
// ===========================================================================
__device__ __forceinline__ void stage_pair(u16* slot, const u16* gA1,
                                           const u16* gB1, int k0, int tid) {
  GLD16(slot + tid * 8, gA1 + k0);                        // A rows 0..127
  GLD16(slot + 4096 + tid * 8, gA1 + 128 * DIMSZ + k0);   // A rows 128..255
  GLD16(slot + 8192 + tid * 8, gB1 + k0);                 // B rows 0..127
  GLD16(slot + 12288 + tid * 8, gB1 + 128 * DIMSZ + k0);  // B rows 128..255
}

__device__ __forceinline__ void gemm_pipe256(
    const u16* __restrict__ A, const u16* __restrict__ Bm,
    int m0, int n0, int tid, u16 (*sm)[16384], f32x4 (*acc)[4])
{
  const int lane = tid & 63, w = tid >> 6;
  const int qd = lane >> 4, l15 = lane & 15;
  const int wm = (w >> 2) * 128, wn = (w & 3) * 64;
  // read-side swizzle: chunk qd ^ ((row>>1)&3); lane-constant (rows 16-aligned)
  const int qdsw = (qd ^ ((l15 >> 1) & 3)) * 8;

  // staging: thread covers row tid>>2 (0..127, +128 for hi), chunk tid&3,
  // source chunk pre-swizzled to match the read-side XOR (rule #21)
  const int srow = tid >> 2;
  const int schk = (tid & 3) ^ ((tid >> 3) & 3);
  const u16* gA1 = A + (size_t)(m0 + srow) * DIMSZ + schk * 8;
  const u16* gB1 = Bm + (size_t)(n0 + srow) * DIMSZ + schk * 8;

  // prologue: stage pairs 0,1; land pair 0, keep pair 1's 4 loads in flight
  stage_pair(sm[0], gA1, gB1, 0, tid);
  stage_pair(sm[1], gA1, gB1, 32, tid);
  asm volatile("s_waitcnt vmcnt(4)" ::: "memory");
  __builtin_amdgcn_s_barrier();
  __builtin_amdgcn_sched_barrier(0);

#pragma unroll 4
  for (int g = 0; g < NPH; ++g) {
    const u16* sA = sm[g & 3];
    const u16* sB = sm[g & 3] + 8192;

    // ---- ds-read 12 frags (this wave's A-half rows + B-half rows) ----
    bf16x8 af[8], bv[4];
#pragma unroll
    for (int mi = 0; mi < 8; ++mi)
      af[mi] = *(const bf16x8*)&sA[(wm + mi * 16 + l15) * 32 + qdsw];
#pragma unroll
    for (int ni = 0; ni < 4; ++ni)
      bv[ni] = *(const bf16x8*)&sB[(wn + ni * 16 + l15) * 32 + qdsw];

    // ---- stage pair g+2 ----
    if (g + 2 < NPH)
      stage_pair(sm[(g + 2) & 3], gA1, gB1, (g + 2) * 32, tid);

    __builtin_amdgcn_sched_barrier(0);
    __builtin_amdgcn_s_barrier();        // pre-MFMA: all reads+stage issued

    __builtin_amdgcn_s_setprio(1);
#pragma unroll
    for (int mi = 0; mi < 8; ++mi)
#pragma unroll
      for (int ni = 0; ni < 4; ++ni)
        acc[mi][ni] = MFMA(af[mi], bv[ni], acc[mi][ni], 0, 0, 0);
    __builtin_amdgcn_s_setprio(0);
    __builtin_amdgcn_sched_barrier(0);

    if (g + 2 < NPH) {
      asm volatile("s_waitcnt vmcnt(4)" ::: "memory");  // pair g+1 landed
    } else if (g + 1 < NPH) {
      asm volatile("s_waitcnt vmcnt(0)" ::: "memory");  // tail drain
    }
    __builtin_amdgcn_s_barrier();        // phase-end
    __builtin_amdgcn_sched_barrier(0);
  }
}

// ---------------------------------------------------------------------------
// Fused QKV projection: A=x16 [16512][1024] (M-tail tile reads <=256 KB past
// the end -> lands in Wqkv16 region, valid memory; stores row-guarded).
// Grid 65*12 flat; nt 0..3 -> q, 4..7 -> k, 8..11 -> v (256 cols each).
// ---------------------------------------------------------------------------
__global__ __launch_bounds__(512, 2) void gemm_qkv(
    const u16* __restrict__ A, const u16* __restrict__ B,
    u16* __restrict__ Cq, u16* __restrict__ Ck, u16* __restrict__ Cv)
{
  __shared__ u16 sm[4][16384];           // 128 KB, 1 WG/CU
  const int tid = threadIdx.x;
  f32x4 acc[8][4];
#pragma unroll
  for (int mi = 0; mi < 8; ++mi)
#pragma unroll
    for (int ni = 0; ni < 4; ++ni)
      acc[mi][ni] = (f32x4){0.f, 0.f, 0.f, 0.f};

  const int wg = xcd_swz(blockIdx.x, 65 * 12);
  const int nt = wg % 12, mt = wg / 12;   // nt fastest: A-tile reuse per XCD
  const int m0 = mt * 256, n0 = nt * 256;

  gemm_pipe256(A, B, m0, n0, tid, sm, acc);

  u16* C = nt < 4 ? Cq : (nt < 8 ? Ck : Cv);
  const int c0 = (nt & 3) * 256;
  const int lane = tid & 63, w = tid >> 6;
  const int qd = lane >> 4, l15 = lane & 15;
  const int wm = (w >> 2) * 128, wn = (w & 3) * 64;
#pragma unroll
  for (int mi = 0; mi < 8; ++mi)
#pragma unroll
    for (int ni = 0; ni < 4; ++ni) {
      const int row0 = m0 + wm + mi * 16 + qd * 4;
      const int col  = c0 + wn + ni * 16 + l15;
#pragma unroll
      for (int r = 0; r < 4; ++r)
        if (row0 + r < MROWS)
          C[(size_t)(row0 + r) * DIMSZ + col] = f2bf(acc[mi][ni][r]);
    }
}

// ---------------------------------------------------------------------------
// gemm_out keeps the r5 128x128 / 3 WG/CU structure (proven; 256x256 would
// hit the 260-block tail-quantization trap).
// ---------------------------------------------------------------------------
__device__ __forceinline__ void stage_sq(u16* slot, const u16* gA,
                                         const u16* gB, int tid) {
  GLD16(slot + tid * 8, gA);                      // A rows 0..63
  GLD16(slot + 2048 + tid * 8, gA + 64 * DIMSZ);  // A rows 64..127
  GLD16(slot + 4096 + tid * 8, gB);               // B rows 0..63
  GLD16(slot + 6144 + tid * 8, gB + 64 * DIMSZ);  // B rows 64..127
}

__device__ __forceinline__ void gemm_pipe_sq(
    const u16* __restrict__ A, const u16* __restrict__ Bm,
    int m0, int n0, int tid, u16 (*sm)[8192], f32x4 (*acc)[4])
{
  const int lane = tid & 63, w = tid >> 6;
  const int qd = lane >> 4, l15 = lane & 15;
  const int wm = (w >> 1) * 64, wn = (w & 1) * 64;
  const int qdsw = (qd ^ ((l15 >> 1) & 3)) * 8;

  const int srow = tid >> 2;                      // 0..63
  const int schk = (tid & 3) ^ ((tid >> 3) & 3);  // source chunk swizzle
  const u16* gA = A + (size_t)(m0 + srow) * DIMSZ + schk * 8;
  const u16* gB = Bm + (size_t)(n0 + srow) * DIMSZ + schk * 8;

  u16 *p0 = sm[0], *p1 = sm[1], *p2 = sm[2];

  stage_sq(p0, gA, gB, tid);
  stage_sq(p1, gA + 32, gB + 32, tid);
  asm volatile("s_waitcnt vmcnt(4)" ::: "memory");
  __builtin_amdgcn_s_barrier();
  __builtin_amdgcn_sched_barrier(0);

  for (int t = 0; t < NKT; ++t) {
    if (t + 2 < NKT)
      stage_sq(p2, gA + (t + 2) * 32, gB + (t + 2) * 32, tid);

    bf16x8 af[4], bv[4];
#pragma unroll
    for (int mi = 0; mi < 4; ++mi)
      af[mi] = *(const bf16x8*)&p0[(wm + mi * 16 + l15) * 32 + qdsw];
#pragma unroll
    for (int ni = 0; ni < 4; ++ni)
      bv[ni] = *(const bf16x8*)&p0[4096 + (wn + ni * 16 + l15) * 32 + qdsw];

    __builtin_amdgcn_s_setprio(1);
#pragma unroll
    for (int mi = 0; mi < 4; ++mi)
#pragma unroll
      for (int ni = 0; ni < 4; ++ni)
        acc[mi][ni] = MFMA(af[mi], bv[ni], acc[mi][ni], 0, 0, 0);
    __builtin_amdgcn_s_setprio(0);

    __builtin_amdgcn_sched_barrier(0);
    if (t + 2 < NKT) {
      asm volatile("s_waitcnt vmcnt(4)" ::: "memory");  // slot t+1 landed
    } else {
      asm volatile("s_waitcnt vmcnt(0)" ::: "memory");
    }
    __builtin_amdgcn_s_barrier();
    __builtin_amdgcn_sched_barrier(0);

    u16* tmp = p0; p0 = p1; p1 = p2; p2 = tmp;   // rotate ring
  }
}

__global__ __launch_bounds__(256, 3) void gemm_out(
    const u16* __restrict__ A, const u16* __restrict__ B,
    float* __restrict__ C, const float* __restrict__ bias)
{
  __shared__ u16 sm[3][8192];
  const int tid = threadIdx.x;
  f32x4 acc[4][4];
#pragma unroll
  for (int mi = 0; mi < 4; ++mi)
#pragma unroll
    for (int ni = 0; ni < 4; ++ni)
      acc[mi][ni] = (f32x4){0.f, 0.f, 0.f, 0.f};

  const int wg = xcd_swz(blockIdx.x, 129 * 8);
  const int nt = wg & 7, mt = wg >> 3;
  const int m0 = mt * 128, n0 = nt * 128;

  gemm_pipe_sq(A, B, m0, n0, tid, sm, acc);

  const int lane = tid & 63, w = tid >> 6;
  const int qd = lane >> 4, l15 = lane & 15;
  const int wm = (w >> 1) * 64, wn = (w & 1) * 64;
#pragma unroll
  for (int mi = 0; mi < 4; ++mi)
#pragma unroll
    for (int ni = 0; ni < 4; ++ni) {
      const int row0 = m0 + wm + mi * 16 + qd * 4;
      const int col  = n0 + wn + ni * 16 + l15;
      float badd = bias[col];
#pragma unroll
      for (int r = 0; r < 4; ++r)
        C[(size_t)(row0 + r) * DIMSZ + col] = acc[mi][ni][r] + badd;
    }
}

// ---------------------------------------------------------------------------
// Global attention among the 32 block-leader tokens, per (b,h).
// 256 threads = 4 waves; wave w owns leader-rows i = w, w+4, ... (8 each).
// Per-wave sp buffer -> ZERO in-loop __syncthreads.
// ---------------------------------------------------------------------------
__global__ __launch_bounds__(256) void global_attn(
    const u16* __restrict__ q, const u16* __restrict__ k,
    const u16* __restrict__ v, float* __restrict__ g)
{
  __shared__ float sQ[NBLK * 64];
  __shared__ float sKT[64 * NBLK];
  __shared__ float sV[NBLK * 64];
  __shared__ float sp[4][NBLK];
  const int b = blockIdx.x >> 4, h = blockIdx.x & 15;
  const int tid = threadIdx.x, lane = tid & 63, w = tid >> 6;

  for (int idx = tid; idx < NBLK * 64; idx += 256) {
    int j = idx >> 6, d = idx & 63;
    size_t off = ((size_t)(b * NTOK + j * BLKSZ)) * DIMSZ + h * 64 + d;
    sQ[idx] = bf2f(q[off]);
    sKT[d * NBLK + j] = bf2f(k[off]);
    sV[idx] = bf2f(v[off]);
  }
  __syncthreads();

  for (int i = w; i < NBLK; i += 4) {
    float s = -3.0e38f;
    if (lane < 32) {
      float acc = 0.f;
      for (int d = 0; d < 64; ++d) acc += sQ[i * 64 + d] * sKT[d * NBLK + lane];
      s = acc * 0.125f;
    }
    float m = s;
    for (int t = 1; t < 64; t <<= 1) m = fmaxf(m, __shfl_xor(m, t));
    float e = (lane < 32) ? __expf(s - m) : 0.f;
    float sum = e;
    for (int t = 1; t < 64; t <<= 1) sum += __shfl_xor(sum, t);
    if (lane < 32) sp[w][lane] = e / sum;
    asm volatile("s_waitcnt lgkmcnt(0)" ::: "memory");  // wave-local LDS RAW
    float acc = 0.f;
    for (int jj = 0; jj < NBLK; ++jj) acc += sp[w][jj] * sV[jj * 64 + lane];
    g[(((size_t)b * NBLK + i) * HEADS + h) * 64 + lane] = acc;
  }
}

// ---------------------------------------------------------------------------
// MFMA block-local attention, 512 threads (8 waves) per (b, blk, h).
// LDS: sS 144xSSTR (43.8 KB), sKV union (20.7 KB) -> 64.5 KB, 2 WG/CU.
// Phase-1 tiles contiguous per wave (q fragments loaded ~2x not ~10x).
// Writes ao IN PLACE over q (disjoint WG slices; q reads precede stores).
// ---------------------------------------------------------------------------
__global__ __launch_bounds__(512) void block_attn(
    const u16* q, const u16* __restrict__ k,
    const u16* __restrict__ v, const float* __restrict__ g,
    u16* ao)
{
  __shared__ u16 sS[144 * SSTR];    // scores then P (bf16)
  __shared__ u16 sKV[144 * KSTR];   // phase1: K [key][d] (KSTR); phase3: V^T [dv][key] (SSTR)
  const int b = blockIdx.x, blk = blockIdx.y, h = blockIdx.z;
  const int tid = threadIdx.x, lane = tid & 63, w = tid >> 6;
  const int qd = lane >> 4, l15 = lane & 15;
  const int h64 = h * 64;
  const size_t row_base = (size_t)b * NTOK + (size_t)blk * BLKSZ;
  const f32x4 zero4 = {0.f, 0.f, 0.f, 0.f};

  // ---- K tile [key][d], rows 129..143 zeroed ----
  {
    const u16x8 zero8 = {0, 0, 0, 0, 0, 0, 0, 0};
    for (int c = tid; c < 144 * 8; c += 512) {
      int row = c >> 3, cc = c & 7;
      u16x8 val = zero8;
      if (row < BLKSZ)
        val = *(const u16x8*)(k + (row_base + row) * DIMSZ + h64 + cc * 8);
      *(u16x8*)&sKV[row * KSTR + cc * 8] = val;
    }
  }
  __syncthreads();

  // ---- phase 1: S = 0.125 * Q K^T; 81 tiles as contiguous per-wave runs ----
  {
    const int tbeg = w * 10;
    const int tend = (w == 7) ? 81 : tbeg + 10;
    int cur_mt = -1;
    bf16x8 qf0, qf1;
    for (int t = tbeg; t < tend; ++t) {
      int mt = t / 9, nt = t - mt * 9;
      if (mt != cur_mt) {
        cur_mt = mt;
        int qrow = mt * 16 + l15;
        if (qrow > 128) qrow = 128;    // clamp: keep reads in-bounds
        const u16* qp = q + (row_base + qrow) * DIMSZ + h64;
        qf0 = *(const bf16x8*)(qp + qd * 8);
        qf1 = *(const bf16x8*)(qp + 32 + qd * 8);
      }
      bf16x8 kf0 = *(const bf16x8*)&sKV[(nt * 16 + l15) * KSTR + qd * 8];
      bf16x8 kf1 = *(const bf16x8*)&sKV[(nt * 16 + l15) * KSTR + 32 + qd * 8];
      f32x4 c = zero4;
      c = MFMA(qf0, kf0, c, 0, 0, 0);
      c = MFMA(qf1, kf1, c, 0, 0, 0);
      int r0 = mt * 16 + qd * 4, col = nt * 16 + l15;
#pragma unroll
      for (int r = 0; r < 4; ++r)
        sS[(r0 + r) * SSTR + col] = f2bf(c[r] * 0.125f);
    }
  }
  __syncthreads();

  // ---- V^T [dv][key] stride SSTR into sKV (K tile dead) ----
  for (int c = tid; c < BLKSZ * 8; c += 512) {
    int row = c >> 3, cc = c & 7;      // row = key index
    u16x8 val = *(const u16x8*)(v + (row_base + row) * DIMSZ + h64 + cc * 8);
#pragma unroll
    for (int jj = 0; jj < 8; ++jj)
      sKV[(cc * 8 + jj) * SSTR + row] = val[jj];
  }

  // ---- softmax over 129 keys (rows over 8 waves) ----
  for (int row = w; row < BLKSZ; row += 8) {
    float x1 = bf2f(sS[row * SSTR + lane]);
    float x2 = bf2f(sS[row * SSTR + 64 + lane]);
    float x3 = (lane == 0) ? bf2f(sS[row * SSTR + 128]) : -3.0e38f;
    float m = fmaxf(fmaxf(x1, x2), x3);
    for (int t = 1; t < 64; t <<= 1) m = fmaxf(m, __shfl_xor(m, t));
    float e1 = __expf(x1 - m), e2 = __expf(x2 - m);
    float e3 = (lane == 0) ? __expf(x3 - m) : 0.f;
    float s = e1 + e2 + e3;
    for (int t = 1; t < 64; t <<= 1) s += __shfl_xor(s, t);
    float inv = 1.f / s;
    sS[row * SSTR + lane] = f2bf(e1 * inv);
    sS[row * SSTR + 64 + lane] = f2bf(e2 * inv);
    if (lane == 0) sS[row * SSTR + 128] = f2bf(e3 * inv);
  }
  __syncthreads();

  // ---- phase 3: out = P V (keys 0..127 MFMA + rank-1 key 128) ----
  for (int t = w; t < 36; t += 8) {
    int mt = t >> 2, nt = t & 3;
    f32x4 c = zero4;
#pragma unroll
    for (int kk = 0; kk < 128; kk += 32) {
      bf16x8 pf = *(const bf16x8*)&sS[(mt * 16 + l15) * SSTR + kk + qd * 8];
      bf16x8 vf = *(const bf16x8*)&sKV[(nt * 16 + l15) * SSTR + kk + qd * 8];
      c = MFMA(pf, vf, c, 0, 0, 0);
    }
    int dv = nt * 16 + l15;
    float v128 = bf2f(sKV[dv * SSTR + 128]);
    int r0 = mt * 16 + qd * 4;
#pragma unroll
    for (int r = 0; r < 4; ++r) {
      int row = r0 + r;
      if (row < BLKSZ) {
        float p128 = bf2f(sS[row * SSTR + 128]);
        float val = c[r] + p128 * v128;
        if (row == 0)
          val += g[(((size_t)b * NBLK + blk) * HEADS + h) * 64 + dv];
        ao[(row_base + row) * DIMSZ + h64 + dv] = f2bf(val);
      }
    }
  }
}

// ---------------------------------------------------------------------------
extern "C" void kernel_launch(void* const* d_in, const int* in_sizes, int n_in,
                              void* d_out, int out_size, void* d_ws, size_t ws_size,
                              hipStream_t stream) {
  // Inputs f32; OUTPUT f32.
  const float* x  = (const float*)d_in[0];
  const float* Wq = (const float*)d_in[1];
  const float* Wk = (const float*)d_in[2];
  const float* Wv = (const float*)d_in[3];
  const float* Wo = (const float*)d_in[4];
  const float* bo = (const float*)d_in[5];
  float* out = (float*)d_out;

  // Scratch:
  //   d_out (67.6 MB) during attention: [k bf16 33.8][v bf16 33.8]
  //   d_ws (74.6 MB peak):
  //     [0,1MB) g | [1,+33.8) qb (ao in-place) | [+33.8) x16 | [+6MB) Wqkv16
  //   Wo16 reuses the x16 region (cast launched after gemm_qkv, stream-ordered).
  char* ws = (char*)d_ws;
  const size_t xb = (size_t)MROWS * DIMSZ * sizeof(u16);   // 33.8 MB
  float* gb     = (float*)ws;
  u16*   qb     = (u16*)(ws + (1u << 20));
  u16*   x16    = (u16*)(ws + (1u << 20) + xb);
  u16*   Wqkv16 = (u16*)(ws + (1u << 20) + 2 * xb);
  u16*   Wo16   = x16;                     // reused after gemm_qkv
  u16*   kb     = (u16*)d_out;
  u16*   vb     = (u16*)d_out + (size_t)MROWS * DIMSZ;

  const int nx = MROWS * DIMSZ;
  const int nw = DIMSZ * DIMSZ;
  cast_f32_bf16<<<nx / 1024, 256, 0, stream>>>(x, x16, nx);
  cast_w3<<<3 * nw / 1024, 256, 0, stream>>>(Wq, Wk, Wv, Wqkv16);

  gemm_qkv<<<dim3(65 * 12), 512, 0, stream>>>(x16, Wqkv16, qb, kb, vb);

  cast_f32_bf16<<<nw / 1024, 256, 0, stream>>>(Wo, Wo16, nw);   // after qkv: x16 dead

  global_attn<<<dim3(BATCH * HEADS), 256, 0, stream>>>(qb, kb, vb, gb);
  block_attn<<<dim3(BATCH, NBLK, HEADS), 512, 0, stream>>>(qb, kb, vb, gb, qb);
  gemm_out<<<dim3(129 * 8), 256, 0, stream>>>(qb, Wo16, out, bo);
}

// Round 7
// 394.517 us; speedup vs baseline: 1.0256x; 1.0256x over previous
//
#include <hip/hip_runtime.h>

typedef unsigned short u16;
typedef __attribute__((ext_vector_type(8))) __bf16 bf16x8;
typedef __attribute__((ext_vector_type(4))) float f32x4;
typedef __attribute__((ext_vector_type(8))) u16 u16x8;
typedef __attribute__((ext_vector_type(4))) u16 u16x4;

#define DIMSZ 1024
#define HEADS 16
#define BLKSZ 129
#define NBLK 32
#define NTOK (BLKSZ * NBLK)      // 4128
#define BATCH 4
#define MROWS (BATCH * NTOK)     // 16512

#define MFMA __builtin_amdgcn_mfma_f32_16x16x32_bf16

#define SSTR 152   // S/P LDS row stride (bf16): 2-way bank alias only (free)
#define KSTR 72    // K tile LDS row stride

#define NKT 32     // K tiles of 32: 1024/32
#define NPH 32     // qkv: 32 K-steps of 32

__device__ __forceinline__ float bf2f(u16 u) {
  return __uint_as_float(((unsigned)u) << 16);
}
__device__ __forceinline__ u16 f2bf(float f) {
  unsigned u = __float_as_uint(f);
  u += 0x7FFFu + ((u >> 16) & 1u);   // round-to-nearest-even
  return (u16)(u >> 16);
}

// async global->LDS, 16B/lane; LDS dest = wave-uniform base + lane*16 (m97)
#define GLD16(ldsp, gp) __builtin_amdgcn_global_load_lds( \
    (const __attribute__((address_space(1))) void*)(gp),   \
    (__attribute__((address_space(3))) void*)(ldsp), 16, 0, 0)

// ---------------------------------------------------------------------------
// Fused input casts: x (16.9M elems) + Wq/Wk/Wv (3M) in ONE launch.
// ---------------------------------------------------------------------------
__global__ __launch_bounds__(256) void cast_in(
    const float* __restrict__ x, const float* __restrict__ wq,
    const float* __restrict__ wk, const float* __restrict__ wv,
    u16* __restrict__ x16, u16* __restrict__ w16)
{
  const int nx = MROWS * DIMSZ, nw = DIMSZ * DIMSZ;
  int i = (blockIdx.x * 256 + threadIdx.x) * 4;
  const float* src;
  u16* dst;
  int j;
  if (i < nx) { src = x; dst = x16; j = i; }
  else {
    int k = i - nx;
    dst = w16; j = k;
    src = (k < nw) ? wq : (k < 2 * nw ? wk : wv);
    j = (k < nw) ? k : (k < 2 * nw ? k - nw : k - 2 * nw);
  }
  float4 f = *(const float4*)(src + j);
  u16x4 o = { f2bf(f.x), f2bf(f.y), f2bf(f.z), f2bf(f.w) };
  *(u16x4*)(dst + (i < nx ? j : (i - nx))) = o;
}

__global__ __launch_bounds__(256) void cast_f32_bf16(
    const float* __restrict__ in, u16* __restrict__ out, int n)
{
  int i = (blockIdx.x * 256 + threadIdx.x) * 4;
  if (i < n) {
    float4 f = *(const float4*)(in + i);
    u16x4 o = { f2bf(f.x), f2bf(f.y), f2bf(f.z), f2bf(f.w) };
    *(u16x4*)(out + i) = o;
  }
}

// ---------------------------------------------------------------------------
// Bijective XCD-aware block swizzle (m204): contiguous logical chunk per XCD.
// ---------------------------------------------------------------------------
__device__ __forceinline__ int xcd_swz(int bid, int nwg) {
  const int xcd = bid & 7, l = bid >> 3;
  const int q = nwg >> 3, r = nwg & 7;
  return (xcd < r ? xcd * (q + 1) : r * (q + 1) + (xcd - r) * q) + l;
}

// ===========================================================================
// QKV: 256x256 tile, BK=32, 512 threads = 8 waves (2M x 4N), wave tile
// 128x64 (acc[8][4]).  REGISTER-PREFETCH pipeline with RAW barriers:
// no ds_read issued in step t is consumed in step t's first MFMA half ->
// the lgkm dependency that serialized rounds 2-6 (LDS then MFMA, strictly
// alternating, MfmaUtil pinned at 33%) is broken.  Per step t:
//   stage(t+3)                          (4 x global_load_lds, vmcnt domain)
//   afH <- slot t rows wm+64..127       (consumed only by 2nd MFMA half)
//   16 MFMA (mi 0..3) on AHEAD frags    (read last step; overlap afH reads)
//   next-AHEAD <- slot t+1              (overlaps 2nd MFMA half)
//   16 MFMA (mi 4..7) on afH
//   vmcnt(4) ; raw s_barrier
// Hazards (distance-3 stage, 4-slot ring):
//  - barrier at end of step s follows per-wave vmcnt(4) with slots s+2,s+3
//    in flight (8 loads) -> retires slot s+2 -> step t's reads of slot t+1
//    are certified by the end-of-(t-1) barrier.
//  - stage(t+3) overwrites slot (t-1)&3; its reads were lgkm-waited by
//    MFMAs in step t-1, before that step's end barrier -> race-free.
// No setprio / no mid-body sched_barrier: the compiler's counted lgkmcnt
// interleave IS the mechanism (m141/m190: fencing it hurts).
// K-accumulation order per acc element unchanged -> bitwise-same output.
// ===========================================================================
__device__ __forceinline__ void stage_pair(u16* slot, const u16* gA1,
                                           const u16* gB1, int k0, int tid) {
  GLD16(slot + tid * 8, gA1 + k0);                        // A rows 0..127
  GLD16(slot + 4096 + tid * 8, gA1 + 128 * DIMSZ + k0);   // A rows 128..255
  GLD16(slot + 8192 + tid * 8, gB1 + k0);                 // B rows 0..127
  GLD16(slot + 12288 + tid * 8, gB1 + 128 * DIMSZ + k0);  // B rows 128..255
}

#define RD8(slot, row, sw) (*(const bf16x8*)&(slot)[(row) * 32 + (sw)])

__global__ __launch_bounds__(512, 1) void gemm_qkv(
    const u16* __restrict__ A, const u16* __restrict__ B,
    u16* __restrict__ Cq, u16* __restrict__ Ck, u16* __restrict__ Cv)
{
  __shared__ u16 sm[4][16384];           // 128 KB, 1 WG/CU
  const int tid = threadIdx.x;
  const int lane = tid & 63, w = tid >> 6;
  const int qd = lane >> 4, l15 = lane & 15;
  const int wm = (w >> 2) * 128, wn = (w & 3) * 64;
  const int qdsw = (qd ^ ((l15 >> 1) & 3)) * 8;   // read-side chunk swizzle

  f32x4 acc[8][4];
#pragma unroll
  for (int mi = 0; mi < 8; ++mi)
#pragma unroll
    for (int ni = 0; ni < 4; ++ni)
      acc[mi][ni] = (f32x4){0.f, 0.f, 0.f, 0.f};

  const int wg = xcd_swz(blockIdx.x, 65 * 12);
  const int nt = wg % 12, mt = wg / 12;   // nt fastest: A-tile reuse per XCD
  const int m0 = mt * 256, n0 = nt * 256;

  // staging source: row tid>>2, chunk pre-swizzled to match read XOR
  const int srow = tid >> 2;
  const int schk = (tid & 3) ^ ((tid >> 3) & 3);
  const u16* gA1 = A + (size_t)(m0 + srow) * DIMSZ + schk * 8;
  const u16* gB1 = B + (size_t)(n0 + srow) * DIMSZ + schk * 8;

  // prologue: stage slots 0,1,2; certify 0,1 (vmcnt(4) retires 8 oldest)
  stage_pair(sm[0], gA1, gB1, 0, tid);
  stage_pair(sm[1], gA1, gB1, 32, tid);
  stage_pair(sm[2], gA1, gB1, 64, tid);
  asm volatile("s_waitcnt vmcnt(4)" ::: "memory");
  __builtin_amdgcn_s_barrier();
  __builtin_amdgcn_sched_barrier(0);

  // pre-read tile 0's ahead set
  bf16x8 afLa[4], bva[4], afLb[4], bvb[4], afH[4];
#pragma unroll
  for (int mi = 0; mi < 4; ++mi) afLa[mi] = RD8(sm[0], wm + mi * 16 + l15, qdsw);
#pragma unroll
  for (int ni = 0; ni < 4; ++ni) bva[ni] = RD8(sm[0] + 8192, wn + ni * 16 + l15, qdsw);

#define QSTEP(T, AC, BC, AN, BN)                                              \
  {                                                                           \
    const u16* slc = sm[(T) & 3];                                             \
    if ((T) + 3 < NPH)                                                        \
      stage_pair(sm[((T) + 3) & 3], gA1, gB1, ((T) + 3) * 32, tid);           \
    _Pragma("unroll")                                                         \
    for (int mi = 0; mi < 4; ++mi)                                            \
      afH[mi] = RD8(slc, wm + 64 + mi * 16 + l15, qdsw);                      \
    _Pragma("unroll")                                                         \
    for (int mi = 0; mi < 4; ++mi)                                            \
      _Pragma("unroll")                                                       \
      for (int ni = 0; ni < 4; ++ni)                                          \
        acc[mi][ni] = MFMA(AC[mi], BC[ni], acc[mi][ni], 0, 0, 0);             \
    if ((T) + 1 < NPH) {                                                      \
      const u16* sln = sm[((T) + 1) & 3];                                     \
      _Pragma("unroll")                                                       \
      for (int mi = 0; mi < 4; ++mi)                                          \
        AN[mi] = RD8(sln, wm + mi * 16 + l15, qdsw);                          \
      _Pragma("unroll")                                                       \
      for (int ni = 0; ni < 4; ++ni)                                          \
        BN[ni] = RD8(sln + 8192, wn + ni * 16 + l15, qdsw);                   \
    }                                                                         \
    _Pragma("unroll")                                                         \
    for (int mi = 0; mi < 4; ++mi)                                            \
      _Pragma("unroll")                                                       \
      for (int ni = 0; ni < 4; ++ni)                                          \
        acc[mi + 4][ni] = MFMA(afH[mi], BC[ni], acc[mi + 4][ni], 0, 0, 0);    \
    __builtin_amdgcn_sched_barrier(0);                                        \
    if ((T) + 3 < NPH) {                                                      \
      asm volatile("s_waitcnt vmcnt(4)" ::: "memory");                        \
    } else {                                                                  \
      asm volatile("s_waitcnt vmcnt(0)" ::: "memory");                        \
    }                                                                         \
    __builtin_amdgcn_s_barrier();                                             \
    __builtin_amdgcn_sched_barrier(0);                                        \
  }

  for (int t = 0; t < NPH; t += 2) {
    QSTEP(t, afLa, bva, afLb, bvb);
    QSTEP(t + 1, afLb, bvb, afLa, bva);
  }
#undef QSTEP

  u16* C = nt < 4 ? Cq : (nt < 8 ? Ck : Cv);
  const int c0 = (nt & 3) * 256;
#pragma unroll
  for (int mi = 0; mi < 8; ++mi)
#pragma unroll
    for (int ni = 0; ni < 4; ++ni) {
      const int row0 = m0 + wm + mi * 16 + qd * 4;
      const int col  = c0 + wn + ni * 16 + l15;
#pragma unroll
      for (int r = 0; r < 4; ++r)
        if (row0 + r < MROWS)
          C[(size_t)(row0 + r) * DIMSZ + col] = f2bf(acc[mi][ni][r]);
    }
}

// ---------------------------------------------------------------------------
// gemm_out keeps the r5 128x128 / 3 WG/CU structure (proven 3-WG TLP).
// ---------------------------------------------------------------------------
__device__ __forceinline__ void stage_sq(u16* slot, const u16* gA,
                                         const u16* gB, int tid) {
  GLD16(slot + tid * 8, gA);                      // A rows 0..63
  GLD16(slot + 2048 + tid * 8, gA + 64 * DIMSZ);  // A rows 64..127
  GLD16(slot + 4096 + tid * 8, gB);               // B rows 0..63
  GLD16(slot + 6144 + tid * 8, gB + 64 * DIMSZ);  // B rows 64..127
}

__device__ __forceinline__ void gemm_pipe_sq(
    const u16* __restrict__ A, const u16* __restrict__ Bm,
    int m0, int n0, int tid, u16 (*sm)[8192], f32x4 (*acc)[4])
{
  const int lane = tid & 63, w = tid >> 6;
  const int qd = lane >> 4, l15 = lane & 15;
  const int wm = (w >> 1) * 64, wn = (w & 1) * 64;
  const int qdsw = (qd ^ ((l15 >> 1) & 3)) * 8;

  const int srow = tid >> 2;                      // 0..63
  const int schk = (tid & 3) ^ ((tid >> 3) & 3);  // source chunk swizzle
  const u16* gA = A + (size_t)(m0 + srow) * DIMSZ + schk * 8;
  const u16* gB = Bm + (size_t)(n0 + srow) * DIMSZ + schk * 8;

  u16 *p0 = sm[0], *p1 = sm[1], *p2 = sm[2];

  stage_sq(p0, gA, gB, tid);
  stage_sq(p1, gA + 32, gB + 32, tid);
  asm volatile("s_waitcnt vmcnt(4)" ::: "memory");
  __builtin_amdgcn_s_barrier();
  __builtin_amdgcn_sched_barrier(0);

  for (int t = 0; t < NKT; ++t) {
    if (t + 2 < NKT)
      stage_sq(p2, gA + (t + 2) * 32, gB + (t + 2) * 32, tid);

    bf16x8 af[4], bv[4];
#pragma unroll
    for (int mi = 0; mi < 4; ++mi)
      af[mi] = *(const bf16x8*)&p0[(wm + mi * 16 + l15) * 32 + qdsw];
#pragma unroll
    for (int ni = 0; ni < 4; ++ni)
      bv[ni] = *(const bf16x8*)&p0[4096 + (wn + ni * 16 + l15) * 32 + qdsw];

    __builtin_amdgcn_s_setprio(1);
#pragma unroll
    for (int mi = 0; mi < 4; ++mi)
#pragma unroll
      for (int ni = 0; ni < 4; ++ni)
        acc[mi][ni] = MFMA(af[mi], bv[ni], acc[mi][ni], 0, 0, 0);
    __builtin_amdgcn_s_setprio(0);

    __builtin_amdgcn_sched_barrier(0);
    if (t + 2 < NKT) {
      asm volatile("s_waitcnt vmcnt(4)" ::: "memory");  // slot t+1 landed
    } else {
      asm volatile("s_waitcnt vmcnt(0)" ::: "memory");
    }
    __builtin_amdgcn_s_barrier();
    __builtin_amdgcn_sched_barrier(0);

    u16* tmp = p0; p0 = p1; p1 = p2; p2 = tmp;   // rotate ring
  }
}

__global__ __launch_bounds__(256, 3) void gemm_out(
    const u16* __restrict__ A, const u16* __restrict__ B,
    float* __restrict__ C, const float* __restrict__ bias)
{
  __shared__ u16 sm[3][8192];
  const int tid = threadIdx.x;
  f32x4 acc[4][4];
#pragma unroll
  for (int mi = 0; mi < 4; ++mi)
#pragma unroll
    for (int ni = 0; ni < 4; ++ni)
      acc[mi][ni] = (f32x4){0.f, 0.f, 0.f, 0.f};

  const int wg = xcd_swz(blockIdx.x, 129 * 8);
  const int nt = wg & 7, mt = wg >> 3;
  const int m0 = mt * 128, n0 = nt * 128;

  gemm_pipe_sq(A, B, m0, n0, tid, sm, acc);

  const int lane = tid & 63, w = tid >> 6;
  const int qd = lane >> 4, l15 = lane & 15;
  const int wm = (w >> 1) * 64, wn = (w & 1) * 64;
#pragma unroll
  for (int mi = 0; mi < 4; ++mi)
#pragma unroll
    for (int ni = 0; ni < 4; ++ni) {
      const int row0 = m0 + wm + mi * 16 + qd * 4;
      const int col  = n0 + wn + ni * 16 + l15;
      float badd = bias[col];
#pragma unroll
      for (int r = 0; r < 4; ++r)
        C[(size_t)(row0 + r) * DIMSZ + col] = acc[mi][ni][r] + badd;
    }
}

// ---------------------------------------------------------------------------
// Global attention among the 32 block-leader tokens, per (b,h).
// 256 threads = 4 waves; per-wave sp -> zero in-loop __syncthreads.
// ---------------------------------------------------------------------------
__global__ __launch_bounds__(256) void global_attn(
    const u16* __restrict__ q, const u16* __restrict__ k,
    const u16* __restrict__ v, float* __restrict__ g)
{
  __shared__ float sQ[NBLK * 64];
  __shared__ float sKT[64 * NBLK];
  __shared__ float sV[NBLK * 64];
  __shared__ float sp[4][NBLK];
  const int b = blockIdx.x >> 4, h = blockIdx.x & 15;
  const int tid = threadIdx.x, lane = tid & 63, w = tid >> 6;

  for (int idx = tid; idx < NBLK * 64; idx += 256) {
    int j = idx >> 6, d = idx & 63;
    size_t off = ((size_t)(b * NTOK + j * BLKSZ)) * DIMSZ + h * 64 + d;
    sQ[idx] = bf2f(q[off]);
    sKT[d * NBLK + j] = bf2f(k[off]);
    sV[idx] = bf2f(v[off]);
  }
  __syncthreads();

  for (int i = w; i < NBLK; i += 4) {
    float s = -3.0e38f;
    if (lane < 32) {
      float acc = 0.f;
      for (int d = 0; d < 64; ++d) acc += sQ[i * 64 + d] * sKT[d * NBLK + lane];
      s = acc * 0.125f;
    }
    float m = s;
    for (int t = 1; t < 64; t <<= 1) m = fmaxf(m, __shfl_xor(m, t));
    float e = (lane < 32) ? __expf(s - m) : 0.f;
    float sum = e;
    for (int t = 1; t < 64; t <<= 1) sum += __shfl_xor(sum, t);
    if (lane < 32) sp[w][lane] = e / sum;
    asm volatile("s_waitcnt lgkmcnt(0)" ::: "memory");  // wave-local LDS RAW
    float acc = 0.f;
    for (int jj = 0; jj < NBLK; ++jj) acc += sp[w][jj] * sV[jj * 64 + lane];
    g[(((size_t)b * NBLK + i) * HEADS + h) * 64 + lane] = acc;
  }
}

// ---------------------------------------------------------------------------
// MFMA block-local attention, 512 threads (8 waves) per (b, blk, h).
// V^T transpose now writes b32 ROW-PAIRS (half the LDS write instructions).
// ---------------------------------------------------------------------------
__global__ __launch_bounds__(512) void block_attn(
    const u16* q, const u16* __restrict__ k,
    const u16* __restrict__ v, const float* __restrict__ g,
    u16* ao)
{
  __shared__ u16 sS[144 * SSTR];    // scores then P (bf16)
  __shared__ u16 sKV[144 * KSTR];   // phase1: K [key][d]; phase3: V^T [dv][key] (SSTR)
  const int b = blockIdx.x, blk = blockIdx.y, h = blockIdx.z;
  const int tid = threadIdx.x, lane = tid & 63, w = tid >> 6;
  const int qd = lane >> 4, l15 = lane & 15;
  const int h64 = h * 64;
  const size_t row_base = (size_t)b * NTOK + (size_t)blk * BLKSZ;
  const f32x4 zero4 = {0.f, 0.f, 0.f, 0.f};

  // ---- K tile [key][d], rows 129..143 zeroed ----
  {
    const u16x8 zero8 = {0, 0, 0, 0, 0, 0, 0, 0};
    for (int c = tid; c < 144 * 8; c += 512) {
      int row = c >> 3, cc = c & 7;
      u16x8 val = zero8;
      if (row < BLKSZ)
        val = *(const u16x8*)(k + (row_base + row) * DIMSZ + h64 + cc * 8);
      *(u16x8*)&sKV[row * KSTR + cc * 8] = val;
    }
  }
  __syncthreads();

  // ---- phase 1: S = 0.125 * Q K^T; 81 tiles as contiguous per-wave runs ----
  {
    const int tbeg = w * 10;
    const int tend = (w == 7) ? 81 : tbeg + 10;
    int cur_mt = -1;
    bf16x8 qf0, qf1;
    for (int t = tbeg; t < tend; ++t) {
      int mt = t / 9, nt = t - mt * 9;
      if (mt != cur_mt) {
        cur_mt = mt;
        int qrow = mt * 16 + l15;
        if (qrow > 128) qrow = 128;    // clamp: keep reads in-bounds
        const u16* qp = q + (row_base + qrow) * DIMSZ + h64;
        qf0 = *(const bf16x8*)(qp + qd * 8);
        qf1 = *(const bf16x8*)(qp + 32 + qd * 8);
      }
      bf16x8 kf0 = *(const bf16x8*)&sKV[(nt * 16 + l15) * KSTR + qd * 8];
      bf16x8 kf1 = *(const bf16x8*)&sKV[(nt * 16 + l15) * KSTR + 32 + qd * 8];
      f32x4 c = zero4;
      c = MFMA(qf0, kf0, c, 0, 0, 0);
      c = MFMA(qf1, kf1, c, 0, 0, 0);
      int r0 = mt * 16 + qd * 4, col = nt * 16 + l15;
#pragma unroll
      for (int r = 0; r < 4; ++r)
        sS[(r0 + r) * SSTR + col] = f2bf(c[r] * 0.125f);
    }
  }
  __syncthreads();

  // ---- V^T [dv][key] stride SSTR into sKV: row-pairs as b32 writes ----
  {
    int c = tid;                       // 512 chunks = 64 row-pairs x 8
    int p = c >> 3, cc = c & 7;        // rows 2p, 2p+1
    u16x8 v0 = *(const u16x8*)(v + (row_base + 2 * p) * DIMSZ + h64 + cc * 8);
    u16x8 v1 = *(const u16x8*)(v + (row_base + 2 * p + 1) * DIMSZ + h64 + cc * 8);
#pragma unroll
    for (int jj = 0; jj < 8; ++jj) {
      unsigned pack = (unsigned)v0[jj] | ((unsigned)v1[jj] << 16);
      *(unsigned*)&sKV[(cc * 8 + jj) * SSTR + 2 * p] = pack;
    }
    if (tid < 8) {                     // row 128 leftover
      u16x8 vl = *(const u16x8*)(v + (row_base + 128) * DIMSZ + h64 + tid * 8);
#pragma unroll
      for (int jj = 0; jj < 8; ++jj)
        sKV[(tid * 8 + jj) * SSTR + 128] = vl[jj];
    }
  }

  // ---- softmax over 129 keys (rows over 8 waves) ----
  for (int row = w; row < BLKSZ; row += 8) {
    float x1 = bf2f(sS[row * SSTR + lane]);
    float x2 = bf2f(sS[row * SSTR + 64 + lane]);
    float x3 = (lane == 0) ? bf2f(sS[row * SSTR + 128]) : -3.0e38f;
    float m = fmaxf(fmaxf(x1, x2), x3);
    for (int t = 1; t < 64; t <<= 1) m = fmaxf(m, __shfl_xor(m, t));
    float e1 = __expf(x1 - m), e2 = __expf(x2 - m);
    float e3 = (lane == 0) ? __expf(x3 - m) : 0.f;
    float s = e1 + e2 + e3;
    for (int t = 1; t < 64; t <<= 1) s += __shfl_xor(s, t);
    float inv = 1.f / s;
    sS[row * SSTR + lane] = f2bf(e1 * inv);
    sS[row * SSTR + 64 + lane] = f2bf(e2 * inv);
    if (lane == 0) sS[row * SSTR + 128] = f2bf(e3 * inv);
  }
  __syncthreads();

  // ---- phase 3: out = P V (keys 0..127 MFMA + rank-1 key 128) ----
  for (int t = w; t < 36; t += 8) {
    int mt = t >> 2, nt = t & 3;
    f32x4 c = zero4;
#pragma unroll
    for (int kk = 0; kk < 128; kk += 32) {
      bf16x8 pf = *(const bf16x8*)&sS[(mt * 16 + l15) * SSTR + kk + qd * 8];
      bf16x8 vf = *(const bf16x8*)&sKV[(nt * 16 + l15) * SSTR + kk + qd * 8];
      c = MFMA(pf, vf, c, 0, 0, 0);
    }
    int dv = nt * 16 + l15;
    float v128 = bf2f(sKV[dv * SSTR + 128]);
    int r0 = mt * 16 + qd * 4;
#pragma unroll
    for (int r = 0; r < 4; ++r) {
      int row = r0 + r;
      if (row < BLKSZ) {
        float p128 = bf2f(sS[row * SSTR + 128]);
        float val = c[r] + p128 * v128;
        if (row == 0)
          val += g[(((size_t)b * NBLK + blk) * HEADS + h) * 64 + dv];
        ao[(row_base + row) * DIMSZ + h64 + dv] = f2bf(val);
      }
    }
  }
}

// ---------------------------------------------------------------------------
extern "C" void kernel_launch(void* const* d_in, const int* in_sizes, int n_in,
                              void* d_out, int out_size, void* d_ws, size_t ws_size,
                              hipStream_t stream) {
  // Inputs f32; OUTPUT f32.
  const float* x  = (const float*)d_in[0];
  const float* Wq = (const float*)d_in[1];
  const float* Wk = (const float*)d_in[2];
  const float* Wv = (const float*)d_in[3];
  const float* Wo = (const float*)d_in[4];
  const float* bo = (const float*)d_in[5];
  float* out = (float*)d_out;

  // Scratch:
  //   d_out (67.6 MB) during attention: [k bf16 33.8][v bf16 33.8]
  //   d_ws (74.6 MB peak):
  //     [0,1MB) g | [1,+33.8) qb (ao in-place) | [+33.8) x16 | [+6MB) Wqkv16
  //   Wo16 reuses the x16 region (cast launched after gemm_qkv, stream-ordered).
  char* ws = (char*)d_ws;
  const size_t xb = (size_t)MROWS * DIMSZ * sizeof(u16);   // 33.8 MB
  float* gb     = (float*)ws;
  u16*   qb     = (u16*)(ws + (1u << 20));
  u16*   x16    = (u16*)(ws + (1u << 20) + xb);
  u16*   Wqkv16 = (u16*)(ws + (1u << 20) + 2 * xb);
  u16*   Wo16   = x16;                     // reused after gemm_qkv
  u16*   kb     = (u16*)d_out;
  u16*   vb     = (u16*)d_out + (size_t)MROWS * DIMSZ;

  const int nx = MROWS * DIMSZ;
  const int nw = DIMSZ * DIMSZ;
  cast_in<<<(nx + 3 * nw) / 1024, 256, 0, stream>>>(x, Wq, Wk, Wv, x16, Wqkv16);

  gemm_qkv<<<dim3(65 * 12), 512, 0, stream>>>(x16, Wqkv16, qb, kb, vb);

  cast_f32_bf16<<<nw / 1024, 256, 0, stream>>>(Wo, Wo16, nw);   // after qkv: x16 dead

  global_attn<<<dim3(BATCH * HEADS), 256, 0, stream>>>(qb, kb, vb, gb);
  block_attn<<<dim3(BATCH, NBLK, HEADS), 512, 0, stream>>>(qb, kb, vb, gb, qb);
  gemm_out<<<dim3(129 * 8), 256, 0, stream>>>(qb, Wo16, out, bo);
}